// Round 1
// baseline (387.579 us; speedup 1.0000x reference)
//
#include <hip/hip_runtime.h>

typedef __bf16 bf16_t;
typedef __bf16 bf16x8 __attribute__((ext_vector_type(8)));
typedef __bf16 bf16x4 __attribute__((ext_vector_type(4)));
typedef float f32x4 __attribute__((ext_vector_type(4)));

#define B_ 2
#define S_ 2048
#define D_ 1024
#define H_ 16
#define HD_ 64

#define MFMA(a, b, c) __builtin_amdgcn_mfma_f32_16x16x32_bf16(a, b, c, 0, 0, 0)

static __device__ __forceinline__ bf16x8 ldb8(const bf16_t* p) {
    return *(const bf16x8*)p;
}

static __device__ __forceinline__ void gload16(const void* g, void* l) {
    __builtin_amdgcn_global_load_lds((const __attribute__((address_space(1))) void*)g,
                                     (__attribute__((address_space(3))) void*)l, 16, 0, 0);
}

// ---------------- fp32 -> bf16 convert ----------------
__global__ __launch_bounds__(256) void k_cvt(const float* __restrict__ in,
                                             bf16_t* __restrict__ out, int n4) {
    int i = blockIdx.x * 256 + threadIdx.x;
    int stride = gridDim.x * 256;
    for (; i < n4; i += stride) {
        float4 v = ((const float4*)in)[i];
        bf16x4 o;
        o[0] = (bf16_t)v.x; o[1] = (bf16_t)v.y; o[2] = (bf16_t)v.z; o[3] = (bf16_t)v.w;
        ((bf16x4*)out)[i] = o;
    }
}

// ---------------- shared GEMM main loop (C = A * Bt^T), 128x128 tile, BK=32 ----
// A: [M,K] bf16 row-major; Bt: [N,K] bf16 row-major. 256 threads = 4 waves (2x2).
// Wave (wm,wn) owns 64x64 = 4x4 fragments of 16x16. acc[i][j] D-layout:
// row = i*16 + 4*(lane>>4) + r, col = j*16 + (lane&15).
static __device__ __forceinline__ void gemm_core(const bf16_t* __restrict__ A,
                                                 const bf16_t* __restrict__ Bt,
                                                 const int K, bf16_t* ldsA, bf16_t* ldsB,
                                                 f32x4 acc[4][4]) {
    const int tid = threadIdx.x;
    const int wave = tid >> 6, lane = tid & 63;
    const int g = lane >> 4, q16 = lane & 15;
    const int wm = wave >> 1, wn = wave & 1;
    const int mb = blockIdx.x * 128, nb = blockIdx.y * 128;
    const int r0 = lane >> 2, c8 = (lane & 3) * 8;

#pragma unroll
    for (int i = 0; i < 4; ++i)
#pragma unroll
        for (int j = 0; j < 4; ++j) {
            f32x4 z = {0.f, 0.f, 0.f, 0.f};
            acc[i][j] = z;
        }

    const bf16_t* ga0 = A + (size_t)(mb + wave * 16 + r0) * K + c8;
    const bf16_t* ga1 = A + (size_t)(mb + 64 + wave * 16 + r0) * K + c8;
    const bf16_t* gb0 = Bt + (size_t)(nb + wave * 16 + r0) * K + c8;
    const bf16_t* gb1 = Bt + (size_t)(nb + 64 + wave * 16 + r0) * K + c8;
    bf16_t* la0 = ldsA + (wave * 16) * 32;
    bf16_t* la1 = ldsA + (64 + wave * 16) * 32;
    bf16_t* lb0 = ldsB + (wave * 16) * 32;
    bf16_t* lb1 = ldsB + (64 + wave * 16) * 32;

    for (int k0 = 0; k0 < K; k0 += 32) {
        gload16(ga0 + k0, la0);
        gload16(ga1 + k0, la1);
        gload16(gb0 + k0, lb0);
        gload16(gb1 + k0, lb1);
        __syncthreads();
        bf16x8 af[4], bfv[4];
#pragma unroll
        for (int i = 0; i < 4; ++i)
            af[i] = ldb8(ldsA + (wm * 64 + i * 16 + q16) * 32 + 8 * g);
#pragma unroll
        for (int j = 0; j < 4; ++j)
            bfv[j] = ldb8(ldsB + (wn * 64 + j * 16 + q16) * 32 + 8 * g);
#pragma unroll
        for (int i = 0; i < 4; ++i)
#pragma unroll
            for (int j = 0; j < 4; ++j)
                acc[i][j] = MFMA(af[i], bfv[j], acc[i][j]);
        __syncthreads();
    }
}

// ---------------- GEMM1: qkv = x @ w_qkv^T + b, fused RoPE, scatter to q/k/vT ----
__global__ __launch_bounds__(256) void k_gemm_qkv(const bf16_t* __restrict__ xb,
                                                  const bf16_t* __restrict__ wqb,
                                                  const float* __restrict__ bqkv,
                                                  const float* __restrict__ rot,
                                                  bf16_t* __restrict__ qa,
                                                  bf16_t* __restrict__ ka,
                                                  bf16_t* __restrict__ vT) {
    __shared__ bf16_t ldsA[128 * 32];
    __shared__ bf16_t ldsB[128 * 32];
    f32x4 acc[4][4];
    gemm_core(xb, wqb, 1024, ldsA, ldsB, acc);

    const int tid = threadIdx.x;
    const int wave = tid >> 6, lane = tid & 63;
    const int g = lane >> 4, q16 = lane & 15;
    const int wm = wave >> 1, wn = wave & 1;
    const int mb = blockIdx.x * 128, nb = blockIdx.y * 128;
    const int third = nb >> 10;  // 0=q, 1=k, 2=v
    const float QS = 0.125f * 1.44269504088896f;  // softmax scale * log2(e)

    if (third < 2) {
        bf16_t* dst = (third == 0) ? qa : ka;
        const float2* cs2 = (const float2*)rot;
#pragma unroll
        for (int j = 0; j < 4; ++j) {
            int n = nb + wn * 64 + j * 16 + q16;
            float bias = bqkv[n];
            int d = n & 1023;
            int h = d >> 6, hd = d & 63;
            int i2 = hd >> 1;
            bool odd = (hd & 1) != 0;
#pragma unroll
            for (int i = 0; i < 4; ++i) {
                int m0 = mb + wm * 64 + i * 16 + 4 * g;
#pragma unroll
                for (int r = 0; r < 4; ++r) {
                    int mm = m0 + r;
                    int s = mm & 2047, b = mm >> 11;
                    float val = acc[i][j][r] + bias;
                    float prt = __shfl_xor(val, 1);
                    float2 cs = cs2[s * 32 + i2];
                    // even dim: re = v*cos - p*sin ; odd dim: ro = p*sin + v*cos
                    float rv = val * cs.x + (odd ? prt * cs.y : -(prt * cs.y));
                    if (third == 0) rv *= QS;
                    dst[((size_t)(b * H_ + h) * S_ + s) * HD_ + hd] = (bf16_t)rv;
                }
            }
        }
    } else {
#pragma unroll
        for (int j = 0; j < 4; ++j) {
            int n = nb + wn * 64 + j * 16 + q16;
            float bias = bqkv[n];
            int d = n & 1023;
            int h = d >> 6, hd = d & 63;
#pragma unroll
            for (int i = 0; i < 4; ++i) {
                int m0 = mb + wm * 64 + i * 16 + 4 * g;
                int s0 = m0 & 2047, b = m0 >> 11;
                bf16x4 pk;
#pragma unroll
                for (int r = 0; r < 4; ++r) pk[r] = (bf16_t)(acc[i][j][r] + bias);
                *(bf16x4*)(vT + ((size_t)(b * H_ + h) * HD_ + hd) * S_ + s0) = pk;
            }
        }
    }
}

// ---------------- flash attention ----------------
// grid (S/64, B*H), 256 threads = 4 independent waves; each wave owns 16 q-rows.
// Scores computed transposed: mfma(A=K-tile, B=Q) -> lane holds S'[t][q=lane&15].
__global__ __launch_bounds__(256) void k_attn(const bf16_t* __restrict__ qa,
                                              const bf16_t* __restrict__ ka,
                                              const bf16_t* __restrict__ vT,
                                              bf16_t* __restrict__ attn) {
    __shared__ bf16_t plds[4][16 * 56];  // padded P-tile per wave (stride 56)
    const int tid = threadIdx.x;
    const int wave = tid >> 6, lane = tid & 63;
    const int g = lane >> 4, q16 = lane & 15;
    const int bh = blockIdx.y;
    const int qrow0 = blockIdx.x * 64 + wave * 16;

    const bf16_t* Qp = qa + ((size_t)bh * S_ + qrow0) * HD_;
    const bf16_t* Kp = ka + (size_t)bh * S_ * HD_;
    const bf16_t* Vp = vT + (size_t)bh * HD_ * S_;
    bf16_t* pl = plds[wave];

    // Q B-fragments (held across whole t-loop): lane holds Q[q=lane&15][8g+32c+j]
    bf16x8 qf0 = ldb8(Qp + q16 * 64 + 8 * g);
    bf16x8 qf1 = ldb8(Qp + q16 * 64 + 8 * g + 32);

    f32x4 o[4];
#pragma unroll
    for (int n = 0; n < 4; ++n) {
        f32x4 z = {0.f, 0.f, 0.f, 0.f};
        o[n] = z;
    }
    float mrow = -__builtin_inff();
    float lsum = 0.f;

    const bf16_t* kp = Kp + q16 * 64 + 8 * g;
    const bf16_t* vp = Vp + q16 * S_ + 8 * g;
    bf16_t* pw0 = pl + q16 * 56 + 4 * g;
    const bf16_t* pr = pl + q16 * 56 + 8 * g;

    for (int t0 = 0; t0 < S_; t0 += 32) {
        // K-tile A-fragments: rows t0+q16 (tileA), t0+16+q16 (tileB); k-chunks 0/32
        bf16x8 a00 = ldb8(kp);
        bf16x8 a01 = ldb8(kp + 32);
        bf16x8 a10 = ldb8(kp + 16 * 64);
        bf16x8 a11 = ldb8(kp + 16 * 64 + 32);
        kp += 32 * 64;
        // V^T B-fragments: lane holds V[t=t0+8g+j][hd=16n+q16]
        bf16x8 v0 = ldb8(vp);
        bf16x8 v1 = ldb8(vp + 16 * S_);
        bf16x8 v2 = ldb8(vp + 32 * S_);
        bf16x8 v3 = ldb8(vp + 48 * S_);
        vp += 32;

        f32x4 sA = {0.f, 0.f, 0.f, 0.f}, sB = {0.f, 0.f, 0.f, 0.f};
        sA = MFMA(a00, qf0, sA);
        sA = MFMA(a01, qf1, sA);
        sB = MFMA(a10, qf0, sB);
        sB = MFMA(a11, qf1, sB);
        // lane holds scores at t = t0 + 4g+r (sA) and t0+16+4g+r (sB), for q = q16.

        float tm = fmaxf(fmaxf(fmaxf(sA[0], sA[1]), fmaxf(sA[2], sA[3])),
                         fmaxf(fmaxf(sB[0], sB[1]), fmaxf(sB[2], sB[3])));
        tm = fmaxf(tm, __shfl_xor(tm, 16));
        tm = fmaxf(tm, __shfl_xor(tm, 32));
        bool grew = tm > mrow;
        float mnew = grew ? tm : mrow;
        float corr = grew ? __builtin_amdgcn_exp2f(mrow - mnew) : 1.0f;

        float p0 = __builtin_amdgcn_exp2f(sA[0] - mnew);
        float p1 = __builtin_amdgcn_exp2f(sA[1] - mnew);
        float p2 = __builtin_amdgcn_exp2f(sA[2] - mnew);
        float p3 = __builtin_amdgcn_exp2f(sA[3] - mnew);
        float p4 = __builtin_amdgcn_exp2f(sB[0] - mnew);
        float p5 = __builtin_amdgcn_exp2f(sB[1] - mnew);
        float p6 = __builtin_amdgcn_exp2f(sB[2] - mnew);
        float p7 = __builtin_amdgcn_exp2f(sB[3] - mnew);
        float ps = ((p0 + p1) + (p2 + p3)) + ((p4 + p5) + (p6 + p7));
        ps += __shfl_xor(ps, 16);
        ps += __shfl_xor(ps, 32);
        lsum = lsum * corr + ps;
        mrow = mnew;

        if (__any(grew)) {
#pragma unroll
            for (int r = 0; r < 4; ++r) {
                float cr = __shfl(corr, 4 * g + r);  // corr for q-row 4g+r
#pragma unroll
                for (int n = 0; n < 4; ++n) o[n][r] *= cr;
            }
        }

        // P transpose via LDS: write [q][t] (t = 4g.., 16+4g..), read A-frag [q][8g..]
        bf16x4 w0, w1;
        w0[0] = (bf16_t)p0; w0[1] = (bf16_t)p1; w0[2] = (bf16_t)p2; w0[3] = (bf16_t)p3;
        w1[0] = (bf16_t)p4; w1[1] = (bf16_t)p5; w1[2] = (bf16_t)p6; w1[3] = (bf16_t)p7;
        *(bf16x4*)pw0 = w0;
        *(bf16x4*)(pw0 + 16) = w1;
        asm volatile("s_waitcnt lgkmcnt(0)" ::: "memory");
        bf16x8 pf = ldb8(pr);

        o[0] = MFMA(pf, v0, o[0]);
        o[1] = MFMA(pf, v1, o[1]);
        o[2] = MFMA(pf, v2, o[2]);
        o[3] = MFMA(pf, v3, o[3]);
    }

    // epilogue: normalize rows and store [b*S+s][h*64+hd] bf16
    const int b = bh >> 4, h = bh & 15;
    bf16_t* op = attn + ((size_t)b * S_ + qrow0) * D_ + h * HD_;
#pragma unroll
    for (int r = 0; r < 4; ++r) {
        float li = __shfl(lsum, 4 * g + r);
        float inv = 1.0f / li;
        int row = 4 * g + r;
#pragma unroll
        for (int n = 0; n < 4; ++n)
            op[(size_t)row * D_ + n * 16 + q16] = (bf16_t)(o[n][r] * inv);
    }
}

// ---------------- GEMM2: out = attn @ w_o^T + b_o (fp32 out) ----------------
__global__ __launch_bounds__(256) void k_gemm_out(const bf16_t* __restrict__ attn,
                                                  const bf16_t* __restrict__ wob,
                                                  const float* __restrict__ bo,
                                                  float* __restrict__ out) {
    __shared__ bf16_t ldsA[128 * 32];
    __shared__ bf16_t ldsB[128 * 32];
    f32x4 acc[4][4];
    gemm_core(attn, wob, 1024, ldsA, ldsB, acc);

    const int tid = threadIdx.x;
    const int wave = tid >> 6, lane = tid & 63;
    const int g = lane >> 4, q16 = lane & 15;
    const int wm = wave >> 1, wn = wave & 1;
    const int mb = blockIdx.x * 128, nb = blockIdx.y * 128;
#pragma unroll
    for (int j = 0; j < 4; ++j) {
        int n = nb + wn * 64 + j * 16 + q16;
        float bias = bo[n];
#pragma unroll
        for (int i = 0; i < 4; ++i) {
            int m0 = mb + wm * 64 + i * 16 + 4 * g;
#pragma unroll
            for (int r = 0; r < 4; ++r)
                out[(size_t)(m0 + r) * D_ + n] = acc[i][j][r] + bias;
        }
    }
}

extern "C" void kernel_launch(void* const* d_in, const int* in_sizes, int n_in,
                              void* d_out, int out_size, void* d_ws, size_t ws_size,
                              hipStream_t stream) {
    const float* x    = (const float*)d_in[0];
    const float* rot  = (const float*)d_in[1];
    const float* wqkv = (const float*)d_in[2];
    const float* bqkv = (const float*)d_in[3];
    const float* wo   = (const float*)d_in[4];
    const float* bo   = (const float*)d_in[5];
    float* out = (float*)d_out;

    char* ws = (char*)d_ws;
    bf16_t* xb   = (bf16_t*)(ws);                        // 8 MB  [4096,1024]
    bf16_t* wqb  = (bf16_t*)(ws + ((size_t)8 << 20));    // 6 MB  [3072,1024]
    bf16_t* wob  = (bf16_t*)(ws + ((size_t)14 << 20));   // 2 MB  [1024,1024]
    bf16_t* qa   = (bf16_t*)(ws + ((size_t)16 << 20));   // 8 MB  [B,H,S,64]
    bf16_t* ka   = (bf16_t*)(ws + ((size_t)24 << 20));   // 8 MB  [B,H,S,64]
    bf16_t* vT   = (bf16_t*)(ws + ((size_t)32 << 20));   // 8 MB  [B,H,64,S]
    bf16_t* attn = (bf16_t*)(ws + ((size_t)40 << 20));   // 8 MB  [4096,1024]

    k_cvt<<<1024, 256, 0, stream>>>(x, xb, (B_ * S_ * D_) / 4);
    k_cvt<<<1024, 256, 0, stream>>>(wqkv, wqb, (3 * D_ * D_) / 4);
    k_cvt<<<1024, 256, 0, stream>>>(wo, wob, (D_ * D_) / 4);
    k_gemm_qkv<<<dim3(32, 24), 256, 0, stream>>>(xb, wqb, bqkv, rot, qa, ka, vT);
    k_attn<<<dim3(32, 32), 256, 0, stream>>>(qa, ka, vT, attn);
    k_gemm_out<<<dim3(32, 8), 256, 0, stream>>>(attn, wob, bo, out);
}

// Round 7
// 276.244 us; speedup vs baseline: 1.4030x; 1.4030x over previous
//
#include <hip/hip_runtime.h>

typedef __bf16 bf16_t;
typedef __bf16 bf16x8 __attribute__((ext_vector_type(8)));
typedef __bf16 bf16x4 __attribute__((ext_vector_type(4)));
typedef __bf16 bf16x2 __attribute__((ext_vector_type(2)));
typedef float f32x4 __attribute__((ext_vector_type(4)));
typedef float f32x16 __attribute__((ext_vector_type(16)));

#define B_ 2
#define S_ 2048
#define D_ 1024
#define H_ 16
#define HD_ 64

#define MFMA(a, b, c) __builtin_amdgcn_mfma_f32_16x16x32_bf16(a, b, c, 0, 0, 0)
#define MFMA32(a, b, c) __builtin_amdgcn_mfma_f32_32x32x16_bf16(a, b, c, 0, 0, 0)

static __device__ __forceinline__ bf16x8 ldb8(const bf16_t* p) {
    return *(const bf16x8*)p;
}

static __device__ __forceinline__ void gload16(const void* g, void* l) {
    __builtin_amdgcn_global_load_lds((const __attribute__((address_space(1))) void*)g,
                                     (__attribute__((address_space(3))) void*)l, 16, 0, 0);
}

// pack two f32 -> one u32 of 2 bf16 (lo=a, hi=b). Plain casts: compiler emits
// v_cvt_pk_bf16_f32 itself; no opaque asm (hazards modeled).
static __device__ __forceinline__ unsigned cvtpk(float a, float b) {
    union { bf16x2 h; unsigned u; } cv;
    cv.h[0] = (bf16_t)a;
    cv.h[1] = (bf16_t)b;
    return cv.u;
}
static __device__ __forceinline__ float xhalf_max(float x) {
    return fmaxf(x, __shfl_xor(x, 32));
}

// ---------------- fp32 -> bf16 convert ----------------
__global__ __launch_bounds__(256) void k_cvt(const float* __restrict__ in,
                                             bf16_t* __restrict__ out, int n4) {
    int i = blockIdx.x * 256 + threadIdx.x;
    int stride = gridDim.x * 256;
    for (; i < n4; i += stride) {
        float4 v = ((const float4*)in)[i];
        bf16x4 o;
        o[0] = (bf16_t)v.x; o[1] = (bf16_t)v.y; o[2] = (bf16_t)v.z; o[3] = (bf16_t)v.w;
        ((bf16x4*)out)[i] = o;
    }
}

// ---------------- shared GEMM main loop (C = A * Bt^T), 128x128 tile, BK=32 ----
static __device__ __forceinline__ void gemm_core(const bf16_t* __restrict__ A,
                                                 const bf16_t* __restrict__ Bt,
                                                 const int K, bf16_t* ldsA, bf16_t* ldsB,
                                                 f32x4 acc[4][4]) {
    const int tid = threadIdx.x;
    const int wave = tid >> 6, lane = tid & 63;
    const int g = lane >> 4, q16 = lane & 15;
    const int wm = wave >> 1, wn = wave & 1;
    const int mb = blockIdx.x * 128, nb = blockIdx.y * 128;
    const int r0 = lane >> 2, c8 = (lane & 3) * 8;

#pragma unroll
    for (int i = 0; i < 4; ++i)
#pragma unroll
        for (int j = 0; j < 4; ++j) {
            f32x4 z = {0.f, 0.f, 0.f, 0.f};
            acc[i][j] = z;
        }

    const bf16_t* ga0 = A + (size_t)(mb + wave * 16 + r0) * K + c8;
    const bf16_t* ga1 = A + (size_t)(mb + 64 + wave * 16 + r0) * K + c8;
    const bf16_t* gb0 = Bt + (size_t)(nb + wave * 16 + r0) * K + c8;
    const bf16_t* gb1 = Bt + (size_t)(nb + 64 + wave * 16 + r0) * K + c8;
    bf16_t* la0 = ldsA + (wave * 16) * 32;
    bf16_t* la1 = ldsA + (64 + wave * 16) * 32;
    bf16_t* lb0 = ldsB + (wave * 16) * 32;
    bf16_t* lb1 = ldsB + (64 + wave * 16) * 32;

    for (int k0 = 0; k0 < K; k0 += 32) {
        gload16(ga0 + k0, la0);
        gload16(ga1 + k0, la1);
        gload16(gb0 + k0, lb0);
        gload16(gb1 + k0, lb1);
        __syncthreads();
        bf16x8 af[4], bfv[4];
#pragma unroll
        for (int i = 0; i < 4; ++i)
            af[i] = ldb8(ldsA + (wm * 64 + i * 16 + q16) * 32 + 8 * g);
#pragma unroll
        for (int j = 0; j < 4; ++j)
            bfv[j] = ldb8(ldsB + (wn * 64 + j * 16 + q16) * 32 + 8 * g);
#pragma unroll
        for (int i = 0; i < 4; ++i)
#pragma unroll
            for (int j = 0; j < 4; ++j)
                acc[i][j] = MFMA(af[i], bfv[j], acc[i][j]);
        __syncthreads();
    }
}

// ---------------- GEMM1: qkv = x @ w_qkv^T + b, fused RoPE, scatter to q/k/vT ----
__global__ __launch_bounds__(256) void k_gemm_qkv(const bf16_t* __restrict__ xb,
                                                  const bf16_t* __restrict__ wqb,
                                                  const float* __restrict__ bqkv,
                                                  const float* __restrict__ rot,
                                                  bf16_t* __restrict__ qa,
                                                  bf16_t* __restrict__ ka,
                                                  bf16_t* __restrict__ vT) {
    __shared__ bf16_t ldsA[128 * 32];
    __shared__ bf16_t ldsB[128 * 32];
    f32x4 acc[4][4];
    gemm_core(xb, wqb, 1024, ldsA, ldsB, acc);

    const int tid = threadIdx.x;
    const int wave = tid >> 6, lane = tid & 63;
    const int g = lane >> 4, q16 = lane & 15;
    const int wm = wave >> 1, wn = wave & 1;
    const int mb = blockIdx.x * 128, nb = blockIdx.y * 128;
    const int third = nb >> 10;  // 0=q, 1=k, 2=v
    const float QS = 0.125f * 1.44269504088896f;  // softmax scale * log2(e)

    if (third < 2) {
        bf16_t* dst = (third == 0) ? qa : ka;
        const float2* cs2 = (const float2*)rot;
#pragma unroll
        for (int j = 0; j < 4; ++j) {
            int n = nb + wn * 64 + j * 16 + q16;
            float bias = bqkv[n];
            int d = n & 1023;
            int h = d >> 6, hd = d & 63;
            int i2 = hd >> 1;
            bool odd = (hd & 1) != 0;
#pragma unroll
            for (int i = 0; i < 4; ++i) {
                int m0 = mb + wm * 64 + i * 16 + 4 * g;
#pragma unroll
                for (int r = 0; r < 4; ++r) {
                    int mm = m0 + r;
                    int s = mm & 2047, b = mm >> 11;
                    float val = acc[i][j][r] + bias;
                    float prt = __shfl_xor(val, 1);
                    float2 cs = cs2[s * 32 + i2];
                    float rv = val * cs.x + (odd ? prt * cs.y : -(prt * cs.y));
                    if (third == 0) rv *= QS;
                    dst[((size_t)(b * H_ + h) * S_ + s) * HD_ + hd] = (bf16_t)rv;
                }
            }
        }
    } else {
#pragma unroll
        for (int j = 0; j < 4; ++j) {
            int n = nb + wn * 64 + j * 16 + q16;
            float bias = bqkv[n];
            int d = n & 1023;
            int h = d >> 6, hd = d & 63;
#pragma unroll
            for (int i = 0; i < 4; ++i) {
                int m0 = mb + wm * 64 + i * 16 + 4 * g;
                int s0 = m0 & 2047, b = m0 >> 11;
                bf16x4 pk;
#pragma unroll
                for (int r = 0; r < 4; ++r) pk[r] = (bf16_t)(acc[i][j][r] + bias);
                *(bf16x4*)(vT + ((size_t)(b * H_ + h) * HD_ + hd) * S_ + s0) = pk;
            }
        }
    }
}

// ---------------- flash attention, 32x32 MFMA, LDS-free softmax ----------------
// Per wave: 32 q-rows, t-tiles of 32. Swapped QK^T (mfma(K,Q)): lane holds
// S'[t][q=lane&31], 16 t-regs at t=(r&3)+8*(r>>2)+4*hi. P redistribution to
// PV A-fragments via packed bf16 pairs + __shfl_xor(32) + hi-select (all
// known-good primitives; no raw asm). l via ones-MFMA (lands in O layout).
static __device__ __forceinline__ void load_kv(const bf16_t* kbase, const bf16_t* vbase,
                                               bf16x8 (&kf)[4], bf16x8 (&vf)[4]) {
#pragma unroll
    for (int j = 0; j < 4; ++j) kf[j] = ldb8(kbase + 16 * j);
    vf[0] = ldb8(vbase);
    vf[1] = ldb8(vbase + 32 * S_);
    vf[2] = ldb8(vbase + 16);
    vf[3] = ldb8(vbase + 16 + 32 * S_);
}

static __device__ __forceinline__ void attn_tile(const bf16x8 (&kf)[4], const bf16x8 (&vf)[4],
                                                 const bf16x8 (&qf)[4], const bf16x8 ones,
                                                 float& m, f32x16& o0, f32x16& o1, f32x16& lac,
                                                 int hi) {
    f32x16 s = {0.f, 0.f, 0.f, 0.f, 0.f, 0.f, 0.f, 0.f,
                0.f, 0.f, 0.f, 0.f, 0.f, 0.f, 0.f, 0.f};
#pragma unroll
    for (int j = 0; j < 4; ++j) s = MFMA32(kf[j], qf[j], s);

    // row max over lane's 16 t, then across lane halves (lane ^ 32 shares q-row)
    float a0 = fmaxf(fmaxf(s[0], s[1]), s[2]);
    float a1 = fmaxf(fmaxf(s[3], s[4]), s[5]);
    float a2 = fmaxf(fmaxf(s[6], s[7]), s[8]);
    float a3 = fmaxf(fmaxf(s[9], s[10]), s[11]);
    float a4 = fmaxf(fmaxf(s[12], s[13]), s[14]);
    float tm = fmaxf(fmaxf(fmaxf(a0, a1), a2), fmaxf(fmaxf(a3, a4), s[15]));
    tm = xhalf_max(tm);

    bool ok = (tm <= m + 8.0f);  // defer-max threshold (exp2 domain)
    if (!__all(ok)) {
        float mn = fmaxf(m, tm);
        float ce = __builtin_amdgcn_exp2f(m - mn);
        m = mn;
#pragma unroll
        for (int r = 0; r < 16; ++r) {
            int q = (r & 3) + 8 * (r >> 2) + 4 * hi;
            float c = __shfl(ce, q);
            o0[r] *= c; o1[r] *= c; lac[r] *= c;
        }
    }

    float p[16];
#pragma unroll
    for (int r = 0; r < 16; ++r) p[r] = __builtin_amdgcn_exp2f(s[r] - m);

    // own packed pairs (this lane's t-slots), and partner-lane (l^32) copies
    unsigned c0 = cvtpk(p[0], p[1]),  c1 = cvtpk(p[2], p[3]);
    unsigned c2 = cvtpk(p[4], p[5]),  c3 = cvtpk(p[6], p[7]);
    unsigned d0 = cvtpk(p[8], p[9]),  d1 = cvtpk(p[10], p[11]);
    unsigned d2 = cvtpk(p[12], p[13]), d3 = cvtpk(p[14], p[15]);
    unsigned x0 = __shfl_xor(c0, 32), x1 = __shfl_xor(c1, 32);
    unsigned x2 = __shfl_xor(c2, 32), x3 = __shfl_xor(c3, 32);
    unsigned y0 = __shfl_xor(d0, 32), y1 = __shfl_xor(d1, 32);
    unsigned y2 = __shfl_xor(d2, 32), y3 = __shfl_xor(d3, 32);

    // A-frag k = 8*hi + jj. pa0: t = k (0..15); pa1: t = 16 + k.
    // hi=0 lane owns t{0-3,8-11}(+pa1 16-19,24-27); hi=1 owns t{4-7,12-15}(...)
    union { unsigned u[4]; bf16x8 v; } pa0, pa1;
    pa0.u[0] = hi ? x2 : c0;  // (t8,t9)|(t0,t1)
    pa0.u[1] = hi ? x3 : c1;  // (t10,t11)|(t2,t3)
    pa0.u[2] = hi ? c2 : x0;  // (t12,t13)|(t4,t5)
    pa0.u[3] = hi ? c3 : x1;  // (t14,t15)|(t6,t7)
    pa1.u[0] = hi ? y2 : d0;
    pa1.u[1] = hi ? y3 : d1;
    pa1.u[2] = hi ? d2 : y0;
    pa1.u[3] = hi ? d3 : y1;

    o0 = MFMA32(pa0.v, vf[0], o0);
    o1 = MFMA32(pa0.v, vf[1], o1);
    o0 = MFMA32(pa1.v, vf[2], o0);
    o1 = MFMA32(pa1.v, vf[3], o1);
    lac = MFMA32(pa0.v, ones, lac);
    lac = MFMA32(pa1.v, ones, lac);
}

__global__ __launch_bounds__(256) void k_attn(const bf16_t* __restrict__ qa,
                                              const bf16_t* __restrict__ ka,
                                              const bf16_t* __restrict__ vT,
                                              bf16_t* __restrict__ attn) {
    const int tid = threadIdx.x;
    const int wave = tid >> 6, lane = tid & 63;
    const int l31 = lane & 31, hi = lane >> 5;
    const int bh = blockIdx.y;
    const int q0 = blockIdx.x * 128 + wave * 32;

    const bf16_t* Qp = qa + ((size_t)bh * S_ + q0) * HD_;
    const bf16_t* Kp = ka + (size_t)bh * S_ * HD_;
    const bf16_t* Vp = vT + (size_t)bh * HD_ * S_;

    bf16x8 qf[4];
    const bf16_t* qptr = Qp + l31 * HD_ + 8 * hi;
#pragma unroll
    for (int j = 0; j < 4; ++j) qf[j] = ldb8(qptr + 16 * j);

    bf16x8 ones;
#pragma unroll
    for (int i = 0; i < 8; ++i) ones[i] = (bf16_t)1.0f;

    const int koff = l31 * HD_ + 8 * hi;
    const int voff = l31 * S_ + 8 * hi;

    f32x16 o0 = {0.f, 0.f, 0.f, 0.f, 0.f, 0.f, 0.f, 0.f,
                 0.f, 0.f, 0.f, 0.f, 0.f, 0.f, 0.f, 0.f};
    f32x16 o1 = o0, lac = o0;
    float m = -1e30f;

    bf16x8 kR0[4], vR0[4], kR1[4], vR1[4];
    load_kv(Kp + koff, Vp + voff, kR0, vR0);

    for (int t0 = 0; t0 < S_; t0 += 64) {
        load_kv(Kp + koff + (t0 + 32) * HD_, Vp + voff + (t0 + 32), kR1, vR1);
        attn_tile(kR0, vR0, qf, ones, m, o0, o1, lac, hi);
        int tn = (t0 + 64) & (S_ - 1);
        load_kv(Kp + koff + tn * HD_, Vp + voff + tn, kR0, vR0);
        attn_tile(kR1, vR1, qf, ones, m, o0, o1, lac, hi);
    }

    // normalize + store: O rows q=(r&3)+8*(r>>2)+4*hi, col hd=l31 (+32 for o1)
    const int b = bh >> 4, h = bh & 15;
    bf16_t* op = attn + ((size_t)b * S_ + q0) * D_ + h * HD_;
#pragma unroll
    for (int r = 0; r < 16; ++r) {
        int q = (r & 3) + 8 * (r >> 2) + 4 * hi;
        float inv = 1.0f / lac[r];
        op[(size_t)q * D_ + l31] = (bf16_t)(o0[r] * inv);
        op[(size_t)q * D_ + 32 + l31] = (bf16_t)(o1[r] * inv);
    }
}

// ---------------- GEMM2: out = attn @ w_o^T + b_o (fp32 out) ----------------
__global__ __launch_bounds__(256) void k_gemm_out(const bf16_t* __restrict__ attn,
                                                  const bf16_t* __restrict__ wob,
                                                  const float* __restrict__ bo,
                                                  float* __restrict__ out) {
    __shared__ bf16_t ldsA[128 * 32];
    __shared__ bf16_t ldsB[128 * 32];
    f32x4 acc[4][4];
    gemm_core(attn, wob, 1024, ldsA, ldsB, acc);

    const int tid = threadIdx.x;
    const int wave = tid >> 6, lane = tid & 63;
    const int g = lane >> 4, q16 = lane & 15;
    const int wm = wave >> 1, wn = wave & 1;
    const int mb = blockIdx.x * 128, nb = blockIdx.y * 128;
#pragma unroll
    for (int j = 0; j < 4; ++j) {
        int n = nb + wn * 64 + j * 16 + q16;
        float bias = bo[n];
#pragma unroll
        for (int i = 0; i < 4; ++i) {
            int m0 = mb + wm * 64 + i * 16 + 4 * g;
#pragma unroll
            for (int r = 0; r < 4; ++r)
                out[(size_t)(m0 + r) * D_ + n] = acc[i][j][r] + bias;
        }
    }
}

extern "C" void kernel_launch(void* const* d_in, const int* in_sizes, int n_in,
                              void* d_out, int out_size, void* d_ws, size_t ws_size,
                              hipStream_t stream) {
    const float* x    = (const float*)d_in[0];
    const float* rot  = (const float*)d_in[1];
    const float* wqkv = (const float*)d_in[2];
    const float* bqkv = (const float*)d_in[3];
    const float* wo   = (const float*)d_in[4];
    const float* bo   = (const float*)d_in[5];
    float* out = (float*)d_out;

    char* ws = (char*)d_ws;
    bf16_t* xb   = (bf16_t*)(ws);                        // 8 MB  [4096,1024]
    bf16_t* wqb  = (bf16_t*)(ws + ((size_t)8 << 20));    // 6 MB  [3072,1024]
    bf16_t* wob  = (bf16_t*)(ws + ((size_t)14 << 20));   // 2 MB  [1024,1024]
    bf16_t* qa   = (bf16_t*)(ws + ((size_t)16 << 20));   // 8 MB  [B,H,S,64]
    bf16_t* ka   = (bf16_t*)(ws + ((size_t)24 << 20));   // 8 MB  [B,H,S,64]
    bf16_t* vT   = (bf16_t*)(ws + ((size_t)32 << 20));   // 8 MB  [B,H,64,S]
    bf16_t* attn = (bf16_t*)(ws + ((size_t)40 << 20));   // 8 MB  [4096,1024]

    k_cvt<<<1024, 256, 0, stream>>>(x, xb, (B_ * S_ * D_) / 4);
    k_cvt<<<1024, 256, 0, stream>>>(wqkv, wqb, (3 * D_ * D_) / 4);
    k_cvt<<<1024, 256, 0, stream>>>(wo, wob, (D_ * D_) / 4);
    k_gemm_qkv<<<dim3(32, 24), 256, 0, stream>>>(xb, wqb, bqkv, rot, qa, ka, vT);
    k_attn<<<dim3(16, 32), 256, 0, stream>>>(qa, ka, vT, attn);
    k_gemm_out<<<dim3(32, 8), 256, 0, stream>>>(attn, wob, bo, out);
}